// Round 10
// baseline (1024.444 us; speedup 1.0000x reference)
//
#include <hip/hip_runtime.h>

#define N_NODES 100000
#define N_EDGES 1600000
#define N_FEAT  256
#define N_HID   64
#define N_CLS   16
#define NB      1563         // ceil(N_NODES/64) row buckets (64 rows each)
#define CHUNK   8192         // edges per scatter block

typedef unsigned short bfraw;
typedef unsigned int uint32;

typedef __attribute__((ext_vector_type(8))) short  bf16x8;
typedef __attribute__((ext_vector_type(4))) float  f32x4;

__device__ __forceinline__ bfraw f2bf(float f) {   // RNE
    union { float f; unsigned int i; } v; v.f = f;
    unsigned int x = v.i;
    return (bfraw)((x + 0x7FFFu + ((x >> 16) & 1u)) >> 16);
}
__device__ __forceinline__ float bf2f(bfraw u) {
    union { unsigned int i; float f; } v; v.i = ((unsigned int)u) << 16; return v.f;
}

// ---------------------------------------------------------------------------
// Pack W1 (fp32 [256][64]) into B-fragment-order bf16 table:
// w1f[((k>>3)*64 + n)*8 + (k&7)] = bf16(W1[k][n])
// ---------------------------------------------------------------------------
__global__ __launch_bounds__(256) void w1cvt_k(const float* __restrict__ W1,
                                               bfraw* __restrict__ w1f) {
    int i = blockIdx.x * 256 + threadIdx.x;          // 16384 total
    int k = i >> 6, n = i & 63;
    w1f[((size_t)((k >> 3) * 64 + n) << 3) + (k & 7)] = f2bf(W1[i]);
}

// ---------------------------------------------------------------------------
// GEMM1 via MFMA, no LDS: h0[100000][64](bf16) = x @ W1 + b1
// wave = 16 rows x 64 cols; 8 K-steps of 32.  (verified r9)
// ---------------------------------------------------------------------------
__global__ __launch_bounds__(256) void gemm1_k(const float* __restrict__ x,
                                               const bfraw* __restrict__ w1f,
                                               const float* __restrict__ b1,
                                               bfraw* __restrict__ h0) {
    const int t    = threadIdx.x;
    const int w    = t >> 6;
    const int lane = t & 63;
    const int q    = lane >> 4;
    const int m    = lane & 15;

    const int row  = blockIdx.x * 64 + w * 16 + m;
    const int srow = row < N_NODES ? row : N_NODES - 1;
    const float* xp = x + (size_t)srow * N_FEAT + q * 8;
    const bf16x8* w1v = (const bf16x8*)w1f;

    f32x4 acc[4];
    #pragma unroll
    for (int nt = 0; nt < 4; ++nt) acc[nt] = (f32x4){0.f, 0.f, 0.f, 0.f};

    #pragma unroll
    for (int s = 0; s < 8; ++s) {
        float4 a0 = *(const float4*)(xp + s * 32);
        float4 a1 = *(const float4*)(xp + s * 32 + 4);
        bf16x8 af;
        af[0] = (short)f2bf(a0.x); af[1] = (short)f2bf(a0.y);
        af[2] = (short)f2bf(a0.z); af[3] = (short)f2bf(a0.w);
        af[4] = (short)f2bf(a1.x); af[5] = (short)f2bf(a1.y);
        af[6] = (short)f2bf(a1.z); af[7] = (short)f2bf(a1.w);
        const int g = s * 4 + q;                 // k-group (k = g*8)
        #pragma unroll
        for (int nt = 0; nt < 4; ++nt) {
            bf16x8 bf_ = w1v[g * 64 + nt * 16 + m];
            acc[nt] = __builtin_amdgcn_mfma_f32_16x16x32_bf16(af, bf_, acc[nt], 0, 0, 0);
        }
    }

    float bb[4];
    #pragma unroll
    for (int nt = 0; nt < 4; ++nt) bb[nt] = b1[nt * 16 + m];

    const int orow0 = blockIdx.x * 64 + w * 16 + q * 4;
    #pragma unroll
    for (int r = 0; r < 4; ++r) {
        int orow = orow0 + r;
        if (orow < N_NODES) {
            bfraw* op = h0 + (size_t)orow * N_HID + m;
            #pragma unroll
            for (int nt = 0; nt < 4; ++nt)
                op[nt * 16] = f2bf(acc[nt][r] + bb[nt]);
        }
    }
}

// ---------------------------------------------------------------------------
// Bucket histogram (row>>6), LDS-staged
// ---------------------------------------------------------------------------
__global__ __launch_bounds__(256) void hist_k(const int* __restrict__ rowi,
                                              int* __restrict__ bcnt) {
    __shared__ int lh[NB];
    for (int i = threadIdx.x; i < NB; i += 256) lh[i] = 0;
    __syncthreads();
    for (int e = blockIdx.x * 256 + threadIdx.x; e < N_EDGES; e += gridDim.x * 256)
        atomicAdd(&lh[rowi[e] >> 6], 1);
    __syncthreads();
    for (int i = threadIdx.x; i < NB; i += 256) {
        int c = lh[i];
        if (c) atomicAdd(&bcnt[i], c);
    }
}

// ---------------------------------------------------------------------------
// Exclusive scan of NB bucket counts -> bbase[0..NB], cursors.
// Single block of 512; each thread serially scans 4 elements.
// ---------------------------------------------------------------------------
__global__ __launch_bounds__(512) void bscan_k(const int* __restrict__ bcnt,
                                               int* __restrict__ bbase,
                                               int* __restrict__ gcur) {
    __shared__ int s[512];
    const int t = threadIdx.x;
    const int base = t * 4;
    int v[4];
    int sum = 0;
    #pragma unroll
    for (int u = 0; u < 4; ++u) {
        int c = (base + u < NB) ? bcnt[base + u] : 0;
        v[u] = sum;                  // exclusive within this thread's chunk
        sum += c;
    }
    s[t] = sum;
    __syncthreads();
    #pragma unroll
    for (int off = 1; off < 512; off <<= 1) {
        int y = (t >= off) ? s[t - off] : 0;
        __syncthreads();
        s[t] += y;
        __syncthreads();
    }
    int excl = s[t] - sum;
    #pragma unroll
    for (int u = 0; u < 4; ++u) {
        int i = base + u;
        if (i <= NB) {
            int p = excl + v[u];
            bbase[i] = p;
            if (i < NB) gcur[i] = p;
        }
    }
}

// ---------------------------------------------------------------------------
// Scatter edges into bucket regions as packed int2 (col | rowlow6<<17, val)
// ---------------------------------------------------------------------------
__global__ __launch_bounds__(256) void scatter_k(const int* __restrict__ rowi,
                                                 const int* __restrict__ coli,
                                                 const float* __restrict__ vals,
                                                 int* __restrict__ gcur,
                                                 int2* __restrict__ edges) {
    __shared__ int lh[NB];
    __shared__ int lb[NB];
    const int t  = threadIdx.x;
    const int e0 = blockIdx.x * CHUNK;
    for (int i = t; i < NB; i += 256) lh[i] = 0;
    __syncthreads();
    for (int j = t; j < CHUNK; j += 256) {
        int e = e0 + j;
        if (e < N_EDGES) atomicAdd(&lh[rowi[e] >> 6], 1);
    }
    __syncthreads();
    for (int i = t; i < NB; i += 256) {
        int c = lh[i];
        lb[i] = c ? atomicAdd(&gcur[i], c) : 0;
        lh[i] = 0;                      // reuse as rank counter
    }
    __syncthreads();
    for (int j = t; j < CHUNK; j += 256) {
        int e = e0 + j;
        if (e < N_EDGES) {
            int r  = rowi[e];
            int b  = r >> 6;
            int rk = atomicAdd(&lh[b], 1);
            edges[lb[b] + rk] = make_int2(coli[e] | ((r & 63) << 17),
                                          __float_as_int(vals[e]));
        }
    }
}

// ---------------------------------------------------------------------------
// SpMM1 per 64-row bucket + fused ReLU + GEMM2:
//   LDS acc[64][65] accumulates h1-tile (wave-per-edge, lane=feature),
//   then h2[64][16] = relu(tile) @ W2 + b2 written directly.
// ---------------------------------------------------------------------------
__global__ __launch_bounds__(256) void spmm1g2_k(const int* __restrict__ bbase,
                                                 const int2* __restrict__ edges,
                                                 const bfraw* __restrict__ h0,
                                                 const float* __restrict__ W2,
                                                 const float* __restrict__ b2,
                                                 float* __restrict__ h2) {
    __shared__ float acc[64 * 65];     // stride 65: atomic phase & epilogue conflict-free
    __shared__ float Ws[64 * 16];
    __shared__ float bs[16];
    const int t    = threadIdx.x;
    const int lane = t & 63;
    const int w    = t >> 6;           // 4 waves

    #pragma unroll
    for (int i = 0; i < 17; ++i) {     // 64*65 = 4160 = 256*16 + 64
        int j = t + i * 256;
        if (j < 64 * 65) acc[j] = 0.f;
    }
    *(float4*)&Ws[t * 4] = *(const float4*)(W2 + t * 4);
    if (t < 16) bs[t] = b2[t];
    __syncthreads();

    const int b   = blockIdx.x;
    const int beg = bbase[b];
    const int end = bbase[b + 1];

    int i = beg + w;
    for (; i + 4 < end; i += 8) {      // 2 edges per wave per iter
        int2 E0 = edges[i];
        int2 E1 = edges[i + 4];
        float g0 = bf2f(h0[(size_t)(E0.x & 0x1FFFF) * N_HID + lane]);
        float g1 = bf2f(h0[(size_t)(E1.x & 0x1FFFF) * N_HID + lane]);
        atomicAdd(&acc[((E0.x >> 17) & 63) * 65 + lane], __int_as_float(E0.y) * g0);
        atomicAdd(&acc[((E1.x >> 17) & 63) * 65 + lane], __int_as_float(E1.y) * g1);
    }
    if (i < end) {
        int2 E = edges[i];
        float g = bf2f(h0[(size_t)(E.x & 0x1FFFF) * N_HID + lane]);
        atomicAdd(&acc[((E.x >> 17) & 63) * 65 + lane], __int_as_float(E.y) * g);
    }
    __syncthreads();

    // epilogue: h2-tile = relu(acc) @ W2 + b2 ; thread = (node, 4 cols)
    const int node = t >> 2;
    const int c0   = (t & 3) * 4;
    float a0 = bs[c0 + 0], a1 = bs[c0 + 1], a2 = bs[c0 + 2], a3 = bs[c0 + 3];
    #pragma unroll
    for (int k = 0; k < 64; ++k) {
        float hval = fmaxf(acc[node * 65 + k], 0.f);
        a0 += hval * Ws[k * 16 + c0 + 0];
        a1 += hval * Ws[k * 16 + c0 + 1];
        a2 += hval * Ws[k * 16 + c0 + 2];
        a3 += hval * Ws[k * 16 + c0 + 3];
    }
    int nr = (b << 6) + node;
    if (nr < N_NODES)
        *(float4*)(h2 + (size_t)nr * N_CLS + c0) = make_float4(a0, a1, a2, a3);
}

// ---------------------------------------------------------------------------
// SpMM2 per 64-row bucket + fused log_softmax. acc stride 17.
// 16 lanes per edge, 4 edges per wave, 4 waves.
// ---------------------------------------------------------------------------
__global__ __launch_bounds__(256) void spmm2_lsm_k(const int* __restrict__ bbase,
                                                   const int2* __restrict__ edges,
                                                   const float* __restrict__ h2,
                                                   float* __restrict__ outp) {
    __shared__ float acc[64 * 17];
    __shared__ float lse[64];
    const int t = threadIdx.x;
    for (int i = t; i < 64 * 17; i += 256) acc[i] = 0.f;
    __syncthreads();

    const int b    = blockIdx.x;
    const int beg  = bbase[b];
    const int end  = bbase[b + 1];
    const int lane = t & 63;
    const int w    = t >> 6;           // 4 waves
    const int sub  = lane >> 4;        // 4 edges/wave
    const int c    = lane & 15;
    const int slot = w * 4 + sub;      // 0..15

    for (int i = beg + slot; i < end; i += 16) {
        int2 E = edges[i];
        float g = h2[(size_t)(E.x & 0x1FFFF) * N_CLS + c];
        atomicAdd(&acc[((E.x >> 17) & 63) * 17 + c], __int_as_float(E.y) * g);
    }
    __syncthreads();

    if (t < 64) {                      // per-row logsumexp
        float v[16];
        float m = -1e30f;
        #pragma unroll
        for (int k = 0; k < 16; ++k) { v[k] = acc[t * 17 + k]; m = fmaxf(m, v[k]); }
        float s = 0.f;
        #pragma unroll
        for (int k = 0; k < 16; ++k) s += expf(v[k] - m);
        lse[t] = m + logf(s);
    }
    __syncthreads();

    const int row0 = b << 6;
    const int nf   = min(64, N_NODES - row0) * N_CLS;
    for (int j = t; j < nf; j += 256)
        outp[(size_t)row0 * N_CLS + j] = acc[(j >> 4) * 17 + (j & 15)] - lse[j >> 4];
}

extern "C" void kernel_launch(void* const* d_in, const int* in_sizes, int n_in,
                              void* d_out, int out_size, void* d_ws, size_t ws_size,
                              hipStream_t stream) {
    const float* x        = (const float*)d_in[0];
    const int*   adj_row  = (const int*)d_in[1];
    const int*   adj_col  = (const int*)d_in[2];
    const float* adj_vals = (const float*)d_in[3];
    const float* W1       = (const float*)d_in[4];
    const float* b1       = (const float*)d_in[5];
    const float* W2       = (const float*)d_in[6];
    const float* b2       = (const float*)d_in[7];
    float*       out      = (float*)d_out;

    // Workspace (~32 MB): h0 bf16 | edges | h2 fp32 | w1f | meta
    const size_t H0_BYTES = (size_t)N_NODES * N_HID * sizeof(bfraw);   // 12.8 MB
    const size_t E_BYTES  = (size_t)N_EDGES * sizeof(int2);            // 12.8 MB
    const size_t H2_BYTES = (size_t)N_NODES * N_CLS * sizeof(float);   // 6.4 MB
    bfraw* h0    = (bfraw*)d_ws;
    int2*  edges = (int2*)((char*)d_ws + H0_BYTES);
    float* h2    = (float*)((char*)edges + E_BYTES);
    bfraw* w1f   = (bfraw*)((char*)h2 + H2_BYTES);     // 16384 bf16 (32 KB), 16B-aligned
    int*   bcnt  = (int*)(w1f + 16384);                // NB
    int*   bbase = bcnt + NB;                          // NB+1
    int*   gcur  = bbase + NB + 1;                     // NB

    // --- bucket build (no sort needed: 64-row buckets, LDS-accumulated SpMM) ---
    hipMemsetAsync(bcnt, 0, NB * sizeof(int), stream);
    hist_k<<<256, 256, 0, stream>>>(adj_row, bcnt);
    bscan_k<<<1, 512, 0, stream>>>(bcnt, bbase, gcur);
    scatter_k<<<(N_EDGES + CHUNK - 1) / CHUNK, 256, 0, stream>>>(adj_row, adj_col,
                                                                 adj_vals, gcur, edges);

    // --- layer 1 + fused relu/GEMM2 ---
    w1cvt_k<<<64, 256, 0, stream>>>(W1, w1f);
    gemm1_k<<<(N_NODES + 63) / 64, 256, 0, stream>>>(x, w1f, b1, h0);
    spmm1g2_k<<<NB, 256, 0, stream>>>(bbase, edges, h0, W2, b2, h2);

    // --- layer 2 (spmm + log_softmax) ---
    spmm2_lsm_k<<<NB, 256, 0, stream>>>(bbase, edges, h2, out);
}